// Round 8
// baseline (437.129 us; speedup 1.0000x reference)
//
#include <hip/hip_runtime.h>

// Problem constants
#define BB 8
#define SS 2048
#define DD 256
#define HH 512
#define LL 3
#define NROWS (BB * SS)
#define NHB 64          // head-chain blocks
#define BARSTRIDE 32    // ints per barrier slot
#define WCB0 64         // first Wc-compute block
#define WCBN 192        // Wc-compute block count (3 layers x 64)

struct Params {
    const float *x, *pw, *pb, *pe, *hebb;
    const float *ai_w, *ai_b, *ao_w, *ao_b, *f1_w, *f1_b, *f2_w, *f2_b;
    const float *ln1w, *ln1b, *ln2w, *ln2b, *nAw, *nAb, *nBw, *nBb;
    const float *p1w, *p1b, *p2w, *p2b;
    float *preds, *A, *Mask, *Psi;
    float *Mc, *T, *V, *T1, *F, *Pp;
    int *bars;
};

// Relaxed agent-scope atomics: reach the coherence point, bypassing the
// non-coherent per-XCD L2s. All cross-block data handoff uses these.
__device__ __forceinline__ float ald(const float* p) {
    return __hip_atomic_load(const_cast<float*>(p), __ATOMIC_RELAXED, __HIP_MEMORY_SCOPE_AGENT);
}
__device__ __forceinline__ void ast(float* p, float v) {
    __hip_atomic_store(p, v, __ATOMIC_RELAXED, __HIP_MEMORY_SCOPE_AGENT);
}

// One-shot barrier. __syncthreads() drains every wave's vmcnt (compiler
// semantics), so all ast data stores are at the coherence point before the
// counter bump. Adaptive spin: fast poll first, then sleep.
__device__ __forceinline__ void barrier_wait(int* slot, int target)
{
    __syncthreads();
    if (threadIdx.x == 0) {
        asm volatile("s_waitcnt vmcnt(0)" ::: "memory");
        __hip_atomic_fetch_add(slot, 1, __ATOMIC_RELAXED, __HIP_MEMORY_SCOPE_AGENT);
        int it = 0;
        while (__hip_atomic_load(slot, __ATOMIC_RELAXED, __HIP_MEMORY_SCOPE_AGENT) < target) {
            if (++it > 64) __builtin_amdgcn_s_sleep(8);
            if (it > (1 << 22)) break;   // hang guard
        }
    }
    __syncthreads();
}

// ---------------------------------------------------------------------------
// Fused single-launch kernel.
// Phases: [M | Wc-idle] -> bar -> [psi+h0 || Wc=Wo@Wv] -> bar ->
//         head chain (64 blocks, 10 quiet barriers; others prestage+park) ->
//         p2 (block 0) -> flag -> all blocks stream A/mask.
// ---------------------------------------------------------------------------
__global__ void __launch_bounds__(256, 4) fused(Params P)
{
    const int bid = blockIdx.x;
    const int tid = threadIdx.x;
    const int ngrid = (int)gridDim.x;

    __shared__ __align__(16) float sX[8 * HH];   // 16 KB multi-purpose staging
    __shared__ float s_m[8], s_r[8], s_rm[8], s_rr[8];

    float* WcA = P.A + 14000000;         // 3x512x512 parked in A (overwritten later)
    float* bcA = WcA + 3 * HH * HH;      // 3x512

    // ---- Phase 1: Mc[k][t] = sum_d pw[d][k]*pe[d][t]; c = pb . pe ----
    if (bid < 16) {
        float* r0s = sX;            // [16][17]
        float* r1s = sX + 272;      // [16][17]
        int kl = tid >> 4, sub = tid & 15;
        int k = bid * 16 + kl;
        float a0 = 0.f, a1 = 0.f;
        #pragma unroll 4
        for (int i = 0; i < 16; ++i) {
            int d = sub * 16 + i;
            float w = P.pw[d * DD + k];
            a0 += w * P.pe[2 * d];
            a1 += w * P.pe[2 * d + 1];
        }
        r0s[kl * 17 + sub] = a0;
        r1s[kl * 17 + sub] = a1;
        __syncthreads();
        if (tid < 16) {
            float s0 = 0.f, s1 = 0.f;
            #pragma unroll
            for (int u = 0; u < 16; ++u) { s0 += r0s[tid * 17 + u]; s1 += r1s[tid * 17 + u]; }
            ast(&P.Mc[2 * (bid * 16 + tid)], s0);
            ast(&P.Mc[2 * (bid * 16 + tid) + 1], s1);
        }
        __syncthreads();
    } else if (bid == 16 && tid < 64) {
        float c0 = 0.f, c1 = 0.f;
        for (int d = tid; d < DD; d += 64) {
            c0 += P.pb[d] * P.pe[2 * d];
            c1 += P.pb[d] * P.pe[2 * d + 1];
        }
        #pragma unroll
        for (int dd = 32; dd; dd >>= 1) { c0 += __shfl_xor(c0, dd); c1 += __shfl_xor(c1, dd); }
        if (tid == 0) { ast(&P.Mc[512], c0); ast(&P.Mc[513], c1); }
    }
    barrier_wait(P.bars + 0 * BARSTRIDE, ngrid);

    // ---- Phase 2: psi+h0 (non-Wc blocks)  ||  Wc = Wo@Wv (blocks 64..255) ----
    if (bid >= WCB0 && bid < WCB0 + WCBN) {
        int wcb = bid - WCB0;
        int l = wcb >> 6;                 // 0..2
        int j0 = (wcb & 63) * 8;          // 8 Wo rows per block
        // stage 8 Wo rows into LDS
        const float* WoB = P.ao_w + (size_t)l * HH * HH;
        for (int idx = tid; idx < 8 * HH; idx += 256) {
            int r = idx >> 9, m = idx & 511;
            sX[idx] = WoB[(size_t)(j0 + r) * HH + m];
        }
        __syncthreads();
        const float* WvB = P.ai_w + ((size_t)l * 3 * HH + 2 * HH) * HH;
        int k0 = tid, k1 = tid + 256;
        float acc0[8] = {0,0,0,0,0,0,0,0};
        float acc1[8] = {0,0,0,0,0,0,0,0};
        for (int m = 0; m < HH; ++m) {
            float w0 = WvB[(size_t)m * HH + k0];
            float w1 = WvB[(size_t)m * HH + k1];
            #pragma unroll
            for (int r = 0; r < 8; ++r) {
                float wo = sX[r * HH + m];
                acc0[r] = fmaf(wo, w0, acc0[r]);
                acc1[r] = fmaf(wo, w1, acc1[r]);
            }
        }
        #pragma unroll
        for (int r = 0; r < 8; ++r) {
            ast(&WcA[((size_t)l * HH + j0 + r) * HH + k0], acc0[r]);
            ast(&WcA[((size_t)l * HH + j0 + r) * HH + k1], acc1[r]);
        }
        if (tid < 8) {
            const float* bvB = P.ai_b + l * 3 * HH + 2 * HH;
            float s = P.ao_b[l * HH + j0 + tid];
            for (int m = 0; m < HH; ++m) s += sX[tid * HH + m] * bvB[m];
            ast(&bcA[l * HH + j0 + tid], s);
        }
    } else {
        int pid = (bid < WCB0) ? bid : bid - WCBN;
        int npsi = ngrid - WCBN;
        int lane = tid & 63, wv = tid >> 6;
        float mc[8];
        #pragma unroll
        for (int i = 0; i < 8; ++i) mc[i] = ald(&P.Mc[lane * 8 + i]);
        float c0 = ald(&P.Mc[512]), c1 = ald(&P.Mc[513]);
        for (int b0 = pid * 16; b0 < NROWS; b0 += npsi * 16) {
            int base = b0 + wv * 4;
            #pragma unroll
            for (int it = 0; it < 4; ++it) {
                int rid = base + it;
                float4 v = *reinterpret_cast<const float4*>(P.x + (size_t)rid * DD + lane * 4);
                float a0 = v.x * mc[0] + v.y * mc[2] + v.z * mc[4] + v.w * mc[6];
                float a1 = v.x * mc[1] + v.y * mc[3] + v.z * mc[5] + v.w * mc[7];
                #pragma unroll
                for (int d = 32; d; d >>= 1) { a0 += __shfl_xor(a0, d); a1 += __shfl_xor(a1, d); }
                a0 += c0;
                a1 += c1;
                float n = sqrtf(a0 * a0 + a1 * a1);
                float scale = 1.f / (n + 1e-8f);
                float r = n * scale;
                #pragma unroll
                for (int i7 = 0; i7 < 7; ++i7) {
                    float f = r / (r + 1e-8f);
                    scale *= f;
                    r *= f;
                }
                float px = a0 * scale, py = a1 * scale;
                if (lane == 0) {
                    ast(&P.Psi[(size_t)rid * 2], px);
                    ast(&P.Psi[(size_t)rid * 2 + 1], py);
                }
                if ((rid & (SS - 1)) == SS - 1) {   // h0 for this batch
                    int b = rid >> 11;
                    for (int j = lane; j < HH; j += 64)
                        ast(&P.T[(size_t)b * HH + j], px * P.hebb[2 * j] + py * P.hebb[2 * j + 1]);
                }
            }
        }
    }
    barrier_wait(P.bars + 1 * BARSTRIDE, ngrid);

    int* flag = P.bars + 480;
    float* sPx = sX;            // store-phase psi staging (split arrays)
    float* sPy = sX + SS;
    const int npb = ngrid >> 3; // store blocks per batch
    const int sb_b = bid / npb;
    const int sb_w = bid - sb_b * npb;

    if (bid >= NHB) {
        // ---- Store blocks: prestage psi[b] into LDS, then park quietly ----
        {
            const float* pbase = P.Psi + (size_t)sb_b * SS * 2;
            for (int idx = tid; idx < SS; idx += 256) {
                sPx[idx] = ald(pbase + idx * 2);
                sPy[idx] = ald(pbase + idx * 2 + 1);
            }
            __syncthreads();
        }
        if (tid == 0) {
            int it = 0;
            while (__hip_atomic_load(flag, __ATOMIC_RELAXED, __HIP_MEMORY_SCOPE_AGENT) == 0) {
                __builtin_amdgcn_s_sleep(32);
                if (++it > (1 << 22)) break;
            }
        }
        __syncthreads();
    } else {
        // ---- Head blocks: 10 serial GEMM stages on a quiet fabric ----
        int sidx = 0;
        auto stage = [&](const float* X, int K,
                         const float* xlnw, const float* xlnb,
                         const float* xln2w, const float* xln2b,
                         const float* W, const float* bias, int wAtomic,
                         const float* res, const float* reslnw, const float* reslnb,
                         float* outp, int J, int G, int act, int barAfter) {
            const int row = tid >> 5, lane = tid & 31;
            const bool doLN = (xlnw != nullptr);
            const bool doRLN = (res != nullptr) && (reslnw != nullptr);
            const bool staged = (K <= HH);

            if (staged) {
                for (int idx = tid; idx < 8 * K; idx += 256)
                    sX[idx] = ald(X + idx);
                __syncthreads();
            }
            if (doLN) {
                float s = 0.f, ss = 0.f;
                for (int k = lane; k < K; k += 32) {
                    float v = sX[row * K + k];
                    s += v; ss += v * v;
                }
                for (int d = 16; d; d >>= 1) { s += __shfl_down(s, d); ss += __shfl_down(ss, d); }
                if (lane == 0) {
                    float m = s / K;
                    s_m[row] = m;
                    s_r[row] = rsqrtf(ss / K - m * m + 1e-5f);
                }
            }
            if (doRLN) {
                float s = 0.f, ss = 0.f;
                for (int k = lane; k < J; k += 32) {
                    float v = ald(res + row * J + k);
                    s += v; ss += v * v;
                }
                for (int d = 16; d; d >>= 1) { s += __shfl_down(s, d); ss += __shfl_down(ss, d); }
                if (lane == 0) {
                    float m = s / J;
                    s_rm[row] = m;
                    s_rr[row] = rsqrtf(ss / J - m * m + 1e-5f);
                }
            }
            __syncthreads();

            if (doLN) {
                for (int idx = tid; idx < 8 * K; idx += 256) {
                    int b = idx / K, k = idx - b * K;
                    sX[idx] = (sX[idx] - s_m[b]) * s_r[b] * xlnw[k] + xlnb[k];
                }
                __syncthreads();
                if (xln2w) {
                    float s = 0.f, ss = 0.f;
                    for (int k = lane; k < K; k += 32) {
                        float v = sX[row * K + k];
                        s += v; ss += v * v;
                    }
                    for (int d = 16; d; d >>= 1) { s += __shfl_down(s, d); ss += __shfl_down(ss, d); }
                    if (lane == 0) {
                        float m = s / K;
                        s_m[row] = m;
                        s_r[row] = rsqrtf(ss / K - m * m + 1e-5f);
                    }
                    __syncthreads();
                    for (int idx = tid; idx < 8 * K; idx += 256) {
                        int b = idx / K, k = idx - b * K;
                        sX[idx] = (sX[idx] - s_m[b]) * s_r[b] * xln2w[k] + xln2b[k];
                    }
                    __syncthreads();
                }
            }

            const int KQ = staged ? K : HH;
            const int nq = K / KQ;
            int chunks = (J * G) / 256;
            if (chunks == 0) chunks = 1;
            for (int c = bid; c < chunks; c += NHB) {
                const int g = tid & (G - 1);
                const int jj = tid / G;
                const int j = c * (256 / G) + jj;
                float acc[8] = {0.f, 0.f, 0.f, 0.f, 0.f, 0.f, 0.f, 0.f};
                for (int q = 0; q < nq; ++q) {
                    if (!staged) {
                        for (int idx = tid; idx < 8 * KQ; idx += 256) {
                            int b = idx / KQ, k = idx - b * KQ;
                            sX[idx] = ald(X + (size_t)b * K + q * KQ + k);
                        }
                        __syncthreads();
                    }
                    if (j < J) {
                        const float* Wrow = W + (size_t)j * K + q * KQ;
                        const int K4q = KQ >> 2;
                        for (int i4 = g; i4 < K4q; i4 += G) {
                            int k = i4 << 2;
                            float4 w4;
                            if (wAtomic) {
                                w4.x = ald(Wrow + k);
                                w4.y = ald(Wrow + k + 1);
                                w4.z = ald(Wrow + k + 2);
                                w4.w = ald(Wrow + k + 3);
                            } else {
                                w4 = *reinterpret_cast<const float4*>(Wrow + k);
                            }
                            #pragma unroll
                            for (int b = 0; b < 8; ++b) {
                                float4 xv = *reinterpret_cast<float4*>(&sX[b * KQ + k]);
                                acc[b] = fmaf(w4.x, xv.x, acc[b]);
                                acc[b] = fmaf(w4.y, xv.y, acc[b]);
                                acc[b] = fmaf(w4.z, xv.z, acc[b]);
                                acc[b] = fmaf(w4.w, xv.w, acc[b]);
                            }
                        }
                    }
                    if (!staged) __syncthreads();
                }
                for (int d = G >> 1; d; d >>= 1) {
                    #pragma unroll
                    for (int b = 0; b < 8; ++b) acc[b] += __shfl_down(acc[b], d);
                }
                if (g == 0 && j < J) {
                    float bs = bias ? (wAtomic ? ald(bias + j) : bias[j]) : 0.f;
                    #pragma unroll
                    for (int b = 0; b < 8; ++b) {
                        float v = acc[b] + bs;
                        if (act) v = v / (1.f + expf(-v));   // silu
                        if (res) {
                            float rv = ald(res + (size_t)b * J + j);
                            if (reslnw) rv = (rv - s_rm[b]) * s_rr[b] * reslnw[j] + reslnb[j];
                            v += rv;
                        }
                        ast(&outp[(size_t)b * J + j], v);
                    }
                }
            }
            if (barAfter) barrier_wait(P.bars + (2 + sidx) * BARSTRIDE, NHB);
            ++sidx;
        };

        for (int l = 0; l < LL; ++l) {
            const float* pxw = l ? P.ln2w + (l - 1) * HH : nullptr;
            const float* pxb = l ? P.ln2b + (l - 1) * HH : nullptr;
            // T1 = LN?(T) + LN?(T) @ Wc^T + bc     (fused v+o)
            stage(P.T, HH, pxw, pxb, nullptr, nullptr,
                  WcA + (size_t)l * HH * HH, bcA + l * HH, 1,
                  P.T, pxw, pxb, P.T1, HH, 32, 0, 1);
            // F = silu(LN1(T1) @ W1^T + b1)
            stage(P.T1, HH, P.ln1w + l * HH, P.ln1b + l * HH, nullptr, nullptr,
                  P.f1_w + (size_t)l * 4 * HH * HH, P.f1_b + l * 4 * HH, 0,
                  nullptr, nullptr, nullptr, P.F, 4 * HH, 16, 1, 1);
            // T = LN1(T1) + F @ W2^T + b2
            stage(P.F, 4 * HH, nullptr, nullptr, nullptr, nullptr,
                  P.f2_w + (size_t)l * HH * 4 * HH, P.f2_b + l * HH, 0,
                  P.T1, P.ln1w + l * HH, P.ln1b + l * HH, P.T, HH, 64, 0, 1);
        }
        // Pp = silu( LN(LN(T,ln2[2]),normA) @ p1^T + p1_b )
        stage(P.T, HH, P.ln2w + 2 * HH, P.ln2b + 2 * HH, P.nAw, P.nAb,
              P.p1w, P.p1b, 0, nullptr, nullptr, nullptr, P.Pp, HH / 2, 32, 1, 1);
        // preds = LN(Pp,normB) @ p2^T + p2_b   (block 0 only; chunks==1)
        if (bid == 0) {
            stage(P.Pp, HH / 2, P.nBw, P.nBb, nullptr, nullptr,
                  P.p2w, P.p2b, 0, nullptr, nullptr, nullptr, P.preds, 1, 32, 0, 0);
            __syncthreads();
            if (tid == 0) {
                asm volatile("s_waitcnt vmcnt(0)" ::: "memory");
                __hip_atomic_store(flag, 1, __ATOMIC_RELAXED, __HIP_MEMORY_SCOPE_AGENT);
            }
        } else {
            if (tid == 0) {
                int it = 0;
                while (__hip_atomic_load(flag, __ATOMIC_RELAXED, __HIP_MEMORY_SCOPE_AGENT) == 0) {
                    __builtin_amdgcn_s_sleep(16);
                    if (++it > (1 << 22)) break;
                }
            }
        }
        __syncthreads();
        // head blocks stage psi now (store blocks prestaged earlier)
        const float* pbase = P.Psi + (size_t)sb_b * SS * 2;
        for (int idx = tid; idx < SS; idx += 256) {
            sPx[idx] = ald(pbase + idx * 2);
            sPy[idx] = ald(pbase + idx * 2 + 1);
        }
        __syncthreads();
    }

    // ---- Phase 4: all blocks stream A/mask ----
    {
        int j0a = tid * 4, j0b = 1024 + tid * 4;
        float4 qxa = *reinterpret_cast<float4*>(&sPx[j0a]);
        float4 qya = *reinterpret_cast<float4*>(&sPy[j0a]);
        float4 qxb = *reinterpret_cast<float4*>(&sPx[j0b]);
        float4 qyb = *reinterpret_cast<float4*>(&sPy[j0b]);
        for (int i = sb_w; i < SS; i += npb) {
            float pix = sPx[i], piy = sPy[i];
            size_t base = ((size_t)sb_b * SS + i) * SS;
            float4 o, m;
            o.x = pix * qxa.x + piy * qya.x;
            o.y = pix * qxa.y + piy * qya.y;
            o.z = pix * qxa.z + piy * qya.z;
            o.w = pix * qxa.w + piy * qya.w;
            *reinterpret_cast<float4*>(P.A + base + j0a) = o;
            m.x = (i == j0a    ) ? 1.f : 0.f;
            m.y = (i == j0a + 1) ? 1.f : 0.f;
            m.z = (i == j0a + 2) ? 1.f : 0.f;
            m.w = (i == j0a + 3) ? 1.f : 0.f;
            *reinterpret_cast<float4*>(P.Mask + base + j0a) = m;
            o.x = pix * qxb.x + piy * qyb.x;
            o.y = pix * qxb.y + piy * qyb.y;
            o.z = pix * qxb.z + piy * qyb.z;
            o.w = pix * qxb.w + piy * qyb.w;
            *reinterpret_cast<float4*>(P.A + base + j0b) = o;
            m.x = (i == j0b    ) ? 1.f : 0.f;
            m.y = (i == j0b + 1) ? 1.f : 0.f;
            m.z = (i == j0b + 2) ? 1.f : 0.f;
            m.w = (i == j0b + 3) ? 1.f : 0.f;
            *reinterpret_cast<float4*>(P.Mask + base + j0b) = m;
        }
    }
}

// ===========================================================================
// Fallback path (verified R3 structure): serial kernels + moonlighted stores.
// ===========================================================================
__device__ __forceinline__ void amask_row(const float* __restrict__ psi,
                                          float* __restrict__ A, float* __restrict__ M,
                                          int blk)
{
    int tid = threadIdx.x;
    int b = blk >> 11, i = blk & (SS - 1);
    float2 pi = *reinterpret_cast<const float2*>(psi + (size_t)blk * 2);
    #pragma unroll
    for (int c = 0; c < 2; ++c) {
        int j0 = c * 1024 + tid * 4;
        const float4* pr = reinterpret_cast<const float4*>(psi + ((size_t)b * SS + j0) * 2);
        float4 q0 = pr[0], q1 = pr[1];
        float4 o;
        o.x = pi.x * q0.x + pi.y * q0.y;
        o.y = pi.x * q0.z + pi.y * q0.w;
        o.z = pi.x * q1.x + pi.y * q1.y;
        o.w = pi.x * q1.z + pi.y * q1.w;
        size_t rb = (size_t)blk * SS + j0;
        *reinterpret_cast<float4*>(A + rb) = o;
        float4 m;
        m.x = (i == j0    ) ? 1.f : 0.f;
        m.y = (i == j0 + 1) ? 1.f : 0.f;
        m.z = (i == j0 + 2) ? 1.f : 0.f;
        m.w = (i == j0 + 3) ? 1.f : 0.f;
        *reinterpret_cast<float4*>(M + rb) = m;
    }
}

__device__ void mm_block(const float* __restrict__ X, int K,
                         const float* __restrict__ xlnw, const float* __restrict__ xlnb,
                         const float* __restrict__ xln2w, const float* __restrict__ xln2b,
                         const float* __restrict__ W, const float* __restrict__ bias,
                         const float* __restrict__ res,
                         const float* __restrict__ reslnw, const float* __restrict__ reslnb,
                         float* __restrict__ out, int J, int G, int act,
                         float* __restrict__ sX,
                         float* s_m, float* s_r, float* s_rm, float* s_rr)
{
    const int tid = threadIdx.x;
    const int bid = blockIdx.x;
    const int row = tid >> 5, lane = tid & 31;
    const bool doLN = (xlnw != nullptr);
    const bool doRLN = (res != nullptr) && (reslnw != nullptr);

    if (doLN) {
        float s = 0.f, ss = 0.f;
        for (int k = lane; k < K; k += 32) {
            float v = X[row * K + k];
            s += v; ss += v * v;
        }
        for (int d = 16; d; d >>= 1) { s += __shfl_down(s, d); ss += __shfl_down(ss, d); }
        if (lane == 0) {
            float m = s / K;
            s_m[row] = m;
            s_r[row] = rsqrtf(ss / K - m * m + 1e-5f);
        }
    }
    if (doRLN) {
        float s = 0.f, ss = 0.f;
        for (int k = lane; k < J; k += 32) {
            float v = res[row * J + k];
            s += v; ss += v * v;
        }
        for (int d = 16; d; d >>= 1) { s += __shfl_down(s, d); ss += __shfl_down(ss, d); }
        if (lane == 0) {
            float m = s / J;
            s_rm[row] = m;
            s_rr[row] = rsqrtf(ss / J - m * m + 1e-5f);
        }
    }
    __syncthreads();

    if (doLN) {
        for (int idx = tid; idx < 8 * K; idx += 256) {
            int b = idx / K, k = idx - b * K;
            sX[idx] = (X[idx] - s_m[b]) * s_r[b] * xlnw[k] + xlnb[k];
        }
        __syncthreads();
        if (xln2w) {
            float s = 0.f, ss = 0.f;
            for (int k = lane; k < K; k += 32) {
                float v = sX[row * K + k];
                s += v; ss += v * v;
            }
            for (int d = 16; d; d >>= 1) { s += __shfl_down(s, d); ss += __shfl_down(ss, d); }
            if (lane == 0) {
                float m = s / K;
                s_m[row] = m;
                s_r[row] = rsqrtf(ss / K - m * m + 1e-5f);
            }
            __syncthreads();
            for (int idx = tid; idx < 8 * K; idx += 256) {
                int b = idx / K, k = idx - b * K;
                sX[idx] = (sX[idx] - s_m[b]) * s_r[b] * xln2w[k] + xln2b[k];
            }
            __syncthreads();
        }
    }

    const float* __restrict__ Xp = doLN ? (const float*)sX : X;
    const int g = tid & (G - 1);
    const int jj = tid / G;
    const int j = bid * (256 / G) + jj;

    float acc[8] = {0.f, 0.f, 0.f, 0.f, 0.f, 0.f, 0.f, 0.f};
    if (j < J) {
        const float4* W4 = reinterpret_cast<const float4*>(W + (size_t)j * K);
        const int K4 = K >> 2;
        for (int i4 = g; i4 < K4; i4 += G) {
            float4 w4 = W4[i4];
            int k = i4 << 2;
            #pragma unroll
            for (int b = 0; b < 8; ++b) {
                float4 xv = *reinterpret_cast<const float4*>(Xp + b * K + k);
                acc[b] = fmaf(w4.x, xv.x, acc[b]);
                acc[b] = fmaf(w4.y, xv.y, acc[b]);
                acc[b] = fmaf(w4.z, xv.z, acc[b]);
                acc[b] = fmaf(w4.w, xv.w, acc[b]);
            }
        }
    }
    for (int d = G >> 1; d; d >>= 1) {
        #pragma unroll
        for (int b = 0; b < 8; ++b) acc[b] += __shfl_down(acc[b], d);
    }
    if (g == 0 && j < J) {
        float bs = bias ? bias[j] : 0.f;
        #pragma unroll
        for (int b = 0; b < 8; ++b) {
            float v = acc[b] + bs;
            if (act) v = v / (1.f + expf(-v));
            if (res) {
                float rv = res[(size_t)b * J + j];
                if (reslnw) rv = (rv - s_rm[b]) * s_rr[b] * reslnw[j] + reslnb[j];
                v += rv;
            }
            out[(size_t)b * J + j] = v;
        }
    }
}

__global__ void compute_M_k(const float* __restrict__ pw, const float* __restrict__ pb,
                            const float* __restrict__ pe, float* __restrict__ Mc)
{
    __shared__ float s0[4][256], s1[4][256];
    int tid = threadIdx.x;
    int k = tid & 255;
    int sub = tid >> 8;
    float a0 = 0.f, a1 = 0.f;
    #pragma unroll 8
    for (int d = sub * 64; d < sub * 64 + 64; ++d) {
        float w = pw[d * DD + k];
        a0 += w * pe[2 * d];
        a1 += w * pe[2 * d + 1];
    }
    s0[sub][k] = a0;
    s1[sub][k] = a1;
    __syncthreads();
    if (tid < 256) {
        Mc[2 * tid]     = s0[0][tid] + s0[1][tid] + s0[2][tid] + s0[3][tid];
        Mc[2 * tid + 1] = s1[0][tid] + s1[1][tid] + s1[2][tid] + s1[3][tid];
    }
    if (tid < 64) {
        float c0 = 0.f, c1 = 0.f;
        for (int d = tid; d < DD; d += 64) {
            c0 += pb[d] * pe[2 * d];
            c1 += pb[d] * pe[2 * d + 1];
        }
        #pragma unroll
        for (int dd = 32; dd; dd >>= 1) { c0 += __shfl_xor(c0, dd); c1 += __shfl_xor(c1, dd); }
        if (tid == 0) { Mc[512] = c0; Mc[513] = c1; }
    }
}

__global__ void psi_k(const float* __restrict__ x, const float* __restrict__ Mc,
                      float* __restrict__ psi)
{
    int tid = threadIdx.x;
    int wave = tid >> 6, lane = tid & 63;
    const float4* Mc4 = reinterpret_cast<const float4*>(Mc);
    float4 mA = Mc4[lane * 2];
    float4 mB = Mc4[lane * 2 + 1];
    float c0 = Mc[512], c1 = Mc[513];
    int base = blockIdx.x * 16 + wave * 4;
    #pragma unroll
    for (int it = 0; it < 4; ++it) {
        int rid = base + it;
        float4 v = *reinterpret_cast<const float4*>(x + (size_t)rid * DD + lane * 4);
        float a0 = v.x * mA.x + v.y * mA.z + v.z * mB.x + v.w * mB.z;
        float a1 = v.x * mA.y + v.y * mA.w + v.z * mB.y + v.w * mB.w;
        #pragma unroll
        for (int d = 32; d; d >>= 1) { a0 += __shfl_xor(a0, d); a1 += __shfl_xor(a1, d); }
        a0 += c0;
        a1 += c1;
        float n = sqrtf(a0 * a0 + a1 * a1);
        float scale = 1.f / (n + 1e-8f);
        float r = n * scale;
        #pragma unroll
        for (int i7 = 0; i7 < 7; ++i7) {
            float f = r / (r + 1e-8f);
            scale *= f;
            r *= f;
        }
        if (lane == 0) {
            float2 pv; pv.x = a0 * scale; pv.y = a1 * scale;
            *reinterpret_cast<float2*>(psi + (size_t)rid * 2) = pv;
        }
    }
}

__global__ void h0_k(const float* __restrict__ psi, const float* __restrict__ hebb,
                     float* __restrict__ h0,
                     float* __restrict__ Ao, float* __restrict__ Mo, int arow0)
{
    int bid = blockIdx.x;
    if (bid >= BB) {
        int r = arow0 + (bid - BB);
        if (r < NROWS) amask_row(psi, Ao, Mo, r);
        return;
    }
    float2 pv = *reinterpret_cast<const float2*>(psi + ((size_t)bid * SS + SS - 1) * 2);
    for (int j = threadIdx.x; j < HH; j += blockDim.x)
        h0[(size_t)bid * HH + j] = pv.x * hebb[2 * j] + pv.y * hebb[2 * j + 1];
}

__global__ void head_mm_k(const float* __restrict__ X, int K,
                          const float* __restrict__ xlnw, const float* __restrict__ xlnb,
                          const float* __restrict__ xln2w, const float* __restrict__ xln2b,
                          const float* __restrict__ W, const float* __restrict__ bias,
                          const float* __restrict__ res,
                          const float* __restrict__ reslnw, const float* __restrict__ reslnb,
                          float* __restrict__ out, int J, int G, int act,
                          const float* __restrict__ psi,
                          float* __restrict__ Ao, float* __restrict__ Mo,
                          int mmBlocks, int arow0)
{
    if ((int)blockIdx.x >= mmBlocks) {
        int r = arow0 + ((int)blockIdx.x - mmBlocks);
        if (r < NROWS) amask_row(psi, Ao, Mo, r);
        return;
    }
    extern __shared__ float sXd[];
    __shared__ float s_m[8], s_r[8], s_rm[8], s_rr[8];
    mm_block(X, K, xlnw, xlnb, xln2w, xln2b, W, bias, res, reslnw, reslnb,
             out, J, G, act, sXd, s_m, s_r, s_rm, s_rr);
}

// ---------------------------------------------------------------------------
extern "C" void kernel_launch(void* const* d_in, const int* in_sizes, int n_in,
                              void* d_out, int out_size, void* d_ws, size_t ws_size,
                              hipStream_t stream)
{
    float* out = (float*)d_out;
    float* ws  = (float*)d_ws;

    Params prm;
    prm.x    = (const float*)d_in[0];
    prm.pw   = (const float*)d_in[1];
    prm.pb   = (const float*)d_in[2];
    prm.pe   = (const float*)d_in[3];
    prm.hebb = (const float*)d_in[4];
    prm.ai_w = (const float*)d_in[5];
    prm.ai_b = (const float*)d_in[6];
    prm.ao_w = (const float*)d_in[7];
    prm.ao_b = (const float*)d_in[8];
    prm.f1_w = (const float*)d_in[9];
    prm.f1_b = (const float*)d_in[10];
    prm.f2_w = (const float*)d_in[11];
    prm.f2_b = (const float*)d_in[12];
    prm.ln1w = (const float*)d_in[13];
    prm.ln1b = (const float*)d_in[14];
    prm.ln2w = (const float*)d_in[15];
    prm.ln2b = (const float*)d_in[16];
    prm.nAw  = (const float*)d_in[17];
    prm.nAb  = (const float*)d_in[18];
    prm.nBw  = (const float*)d_in[19];
    prm.nBb  = (const float*)d_in[20];
    prm.p1w  = (const float*)d_in[21];
    prm.p1b  = (const float*)d_in[22];
    prm.p2w  = (const float*)d_in[23];
    prm.p2b  = (const float*)d_in[24];

    // output layout: preds(8) | A(B*S*S) | mask(B*S*S) | psi(B*S*2)
    prm.preds = out;
    prm.A     = out + 8;
    prm.Mask  = out + 8 + (size_t)BB * SS * SS;
    prm.Psi   = out + 8 + (size_t)2 * BB * SS * SS;

    // ws layout: bars (512 ints) | Mc | T | T1 | F | Pp | V(fallback)
    prm.bars = (int*)ws;
    prm.Mc = ws + 512;
    prm.T  = ws + 1280;
    prm.T1 = ws + 5376;
    prm.F  = ws + 9472;
    prm.Pp = ws + 25856;
    prm.V  = ws + 27904;

    // zero the barrier slots each call (graph-capturable)
    hipMemsetAsync(d_ws, 0, 2048, stream);

    // --- cooperative fused path ---
    hipError_t le = hipErrorUnknown;
    int maxB = 0;
    hipError_t oe = hipOccupancyMaxActiveBlocksPerMultiprocessor(
        &maxB, (const void*)fused, 256, 0);
    if (oe == hipSuccess && maxB > 0) {
        int grid = maxB * 256;
        if (grid > 1024) grid = 1024;
        grid -= grid % 8;
        if (grid >= 384) {
            void* args[] = { &prm };
            le = hipLaunchCooperativeKernel((const void*)fused, dim3(grid), dim3(256),
                                            args, 0, stream);
        }
    }
    if (le == hipSuccess) return;

    // --- fallback: verified multi-kernel path ---
    compute_M_k<<<1, 1024, 0, stream>>>(prm.pw, prm.pb, prm.pe, prm.Mc);
    psi_k<<<NROWS / 16, 256, 0, stream>>>(prm.x, prm.Mc, prm.Psi);

    int ci = 0, arow = 0;
    auto nextq = [&]() { int q = 1092 + (ci < 4 ? 1 : 0); ++ci; return q; };

    {
        int q = nextq();
        h0_k<<<BB + q, 256, 0, stream>>>(prm.Psi, prm.hebb, prm.T, prm.A, prm.Mask, arow);
        arow += q;
    }
    for (int l = 0; l < LL; ++l) {
        const float* pxw = l ? prm.ln2w + (l - 1) * HH : nullptr;
        const float* pxb = l ? prm.ln2b + (l - 1) * HH : nullptr;
        int q;
        q = nextq();
        head_mm_k<<<64 + q, 256, (pxw ? 8 * HH * 4 : 0), stream>>>(
            prm.T, HH, pxw, pxb, nullptr, nullptr,
            prm.ai_w + ((size_t)l * 3 * HH + 2 * HH) * HH, prm.ai_b + l * 3 * HH + 2 * HH,
            nullptr, nullptr, nullptr, prm.V, HH, 32, 0,
            prm.Psi, prm.A, prm.Mask, 64, arow);
        arow += q;
        q = nextq();
        head_mm_k<<<64 + q, 256, 0, stream>>>(
            prm.V, HH, nullptr, nullptr, nullptr, nullptr,
            prm.ao_w + (size_t)l * HH * HH, prm.ao_b + l * HH,
            prm.T, pxw, pxb, prm.T1, HH, 32, 0,
            prm.Psi, prm.A, prm.Mask, 64, arow);
        arow += q;
        q = nextq();
        head_mm_k<<<128 + q, 256, 8 * HH * 4, stream>>>(
            prm.T1, HH, prm.ln1w + l * HH, prm.ln1b + l * HH, nullptr, nullptr,
            prm.f1_w + (size_t)l * 4 * HH * HH, prm.f1_b + l * 4 * HH,
            nullptr, nullptr, nullptr, prm.F, 4 * HH, 16, 1,
            prm.Psi, prm.A, prm.Mask, 128, arow);
        arow += q;
        q = nextq();
        head_mm_k<<<128 + q, 256, 0, stream>>>(
            prm.F, 4 * HH, nullptr, nullptr, nullptr, nullptr,
            prm.f2_w + (size_t)l * HH * 4 * HH, prm.f2_b + l * HH,
            prm.T1, prm.ln1w + l * HH, prm.ln1b + l * HH, prm.T, HH, 64, 0,
            prm.Psi, prm.A, prm.Mask, 128, arow);
        arow += q;
    }
    {
        int q = nextq();
        head_mm_k<<<32 + q, 256, 8 * HH * 4, stream>>>(
            prm.T, HH, prm.ln2w + 2 * HH, prm.ln2b + 2 * HH, prm.nAw, prm.nAb,
            prm.p1w, prm.p1b, nullptr, nullptr, nullptr, prm.Pp, HH / 2, 32, 1,
            prm.Psi, prm.A, prm.Mask, 32, arow);
        arow += q;
    }
    {
        int q = nextq();
        head_mm_k<<<1 + q, 256, 8 * (HH / 2) * 4, stream>>>(
            prm.Pp, HH / 2, prm.nBw, prm.nBb, nullptr, nullptr,
            prm.p2w, prm.p2b, nullptr, nullptr, nullptr, prm.preds, 1, 32, 0,
            prm.Psi, prm.A, prm.Mask, 1, arow);
        arow += q;
    }
}

// Round 10
// 204.972 us; speedup vs baseline: 2.1326x; 2.1326x over previous
//
#include <hip/hip_runtime.h>
#include <hip/hip_bf16.h>

// Problem constants
#define BB 8
#define SS 2048
#define DD 256
#define HH 512
#define LL 3
#define NROWS (BB * SS)

// Native clang vector type: accepted by __builtin_nontemporal_store
typedef float floatx4 __attribute__((ext_vector_type(4)));

// ---------------------------------------------------------------------------
// A/mask row worker: A[b,i,j] = psi[b,i,:].psi[b,j,:] ; mask = (i==j).
// One block (256 threads) per row; dense float4 NON-TEMPORAL stores (bypass
// L2 so launch boundaries have nothing to write back).
// ---------------------------------------------------------------------------
__device__ __forceinline__ void amask_row(const float* __restrict__ psi,
                                          float* __restrict__ A, float* __restrict__ M,
                                          int blk)
{
    int tid = threadIdx.x;
    int b = blk >> 11, i = blk & (SS - 1);
    float2 pi = *reinterpret_cast<const float2*>(psi + (size_t)blk * 2);
    #pragma unroll
    for (int c = 0; c < 2; ++c) {
        int j0 = c * 1024 + tid * 4;
        const float4* pr = reinterpret_cast<const float4*>(psi + ((size_t)b * SS + j0) * 2);
        float4 q0 = pr[0], q1 = pr[1];
        floatx4 o;
        o.x = pi.x * q0.x + pi.y * q0.y;
        o.y = pi.x * q0.z + pi.y * q0.w;
        o.z = pi.x * q1.x + pi.y * q1.y;
        o.w = pi.x * q1.z + pi.y * q1.w;
        size_t rb = (size_t)blk * SS + j0;
        __builtin_nontemporal_store(o, reinterpret_cast<floatx4*>(A + rb));
        floatx4 m;
        m.x = (i == j0    ) ? 1.f : 0.f;
        m.y = (i == j0 + 1) ? 1.f : 0.f;
        m.z = (i == j0 + 2) ? 1.f : 0.f;
        m.w = (i == j0 + 3) ? 1.f : 0.f;
        __builtin_nontemporal_store(m, reinterpret_cast<floatx4*>(M + rb));
    }
}

// ---------------------------------------------------------------------------
// Kernel 0: M[k][t] = sum_d proj_w[d][k] * pe[d][t];  c[t] = sum_d proj_b[d]*pe[d][t]
// Mc layout: M interleaved [k*2+t] (512 floats), then c0,c1 at [512],[513]
// ---------------------------------------------------------------------------
__global__ void compute_M(const float* __restrict__ pw, const float* __restrict__ pb,
                          const float* __restrict__ pe, float* __restrict__ Mc)
{
    __shared__ float s0[4][256], s1[4][256];
    int tid = threadIdx.x;          // 0..1023
    int k = tid & 255;
    int sub = tid >> 8;             // 0..3
    float a0 = 0.f, a1 = 0.f;
    #pragma unroll 8
    for (int d = sub * 64; d < sub * 64 + 64; ++d) {
        float w = pw[d * DD + k];   // wave-contiguous in k
        a0 += w * pe[2 * d];
        a1 += w * pe[2 * d + 1];
    }
    s0[sub][k] = a0;
    s1[sub][k] = a1;
    __syncthreads();
    if (tid < 256) {
        Mc[2 * tid]     = s0[0][tid] + s0[1][tid] + s0[2][tid] + s0[3][tid];
        Mc[2 * tid + 1] = s1[0][tid] + s1[1][tid] + s1[2][tid] + s1[3][tid];
    }
    if (tid < 64) {
        float c0 = 0.f, c1 = 0.f;
        for (int d = tid; d < DD; d += 64) {
            c0 += pb[d] * pe[2 * d];
            c1 += pb[d] * pe[2 * d + 1];
        }
        #pragma unroll
        for (int dd = 32; dd; dd >>= 1) {
            c0 += __shfl_xor(c0, dd);
            c1 += __shfl_xor(c1, dd);
        }
        if (tid == 0) { Mc[512] = c0; Mc[513] = c1; }
    }
}

// ---------------------------------------------------------------------------
// Kernel 1: psi = normalize(x @ M + c) then 7 diffusion rescales (force==0).
// One wave per row; each wave does 4 rows.
// ---------------------------------------------------------------------------
__global__ void psi_kernel(const float* __restrict__ x, const float* __restrict__ Mc,
                           float* __restrict__ psi)
{
    int tid = threadIdx.x;
    int wave = tid >> 6, lane = tid & 63;
    const float4* Mc4 = reinterpret_cast<const float4*>(Mc);
    float4 mA = Mc4[lane * 2];
    float4 mB = Mc4[lane * 2 + 1];
    float c0 = Mc[512], c1 = Mc[513];
    int base = blockIdx.x * 16 + wave * 4;
    #pragma unroll
    for (int it = 0; it < 4; ++it) {
        int rid = base + it;
        float4 v = *reinterpret_cast<const float4*>(x + (size_t)rid * DD + lane * 4);
        float a0 = v.x * mA.x + v.y * mA.z + v.z * mB.x + v.w * mB.z;
        float a1 = v.x * mA.y + v.y * mA.w + v.z * mB.y + v.w * mB.w;
        #pragma unroll
        for (int d = 32; d; d >>= 1) {
            a0 += __shfl_xor(a0, d);
            a1 += __shfl_xor(a1, d);
        }
        a0 += c0;
        a1 += c1;
        float n = sqrtf(a0 * a0 + a1 * a1);
        float scale = 1.f / (n + 1e-8f);
        float r = n * scale;
        #pragma unroll
        for (int i7 = 0; i7 < 7; ++i7) {
            float f = r / (r + 1e-8f);
            scale *= f;
            r *= f;
        }
        if (lane == 0) {
            float2 pv;
            pv.x = a0 * scale;
            pv.y = a1 * scale;
            *reinterpret_cast<float2*>(psi + (size_t)rid * 2) = pv;
        }
    }
}

// ---------------------------------------------------------------------------
// Kernel 1b: h0[b,j] = psi[b,S-1,:].hebb[j,:]  (+ moonlighted A/mask rows)
// ---------------------------------------------------------------------------
__global__ void h0_kernel(const float* __restrict__ psi, const float* __restrict__ hebb,
                          float* __restrict__ h0,
                          float* __restrict__ Ao, float* __restrict__ Mo, int arow0)
{
    int bid = blockIdx.x;
    if (bid >= BB) {
        int r = arow0 + (bid - BB);
        if (r < NROWS) amask_row(psi, Ao, Mo, r);
        return;
    }
    float2 pv = *reinterpret_cast<const float2*>(psi + ((size_t)bid * SS + SS - 1) * 2);
    for (int j = threadIdx.x; j < HH; j += blockDim.x)
        h0[(size_t)bid * HH + j] = pv.x * hebb[2 * j] + pv.y * hebb[2 * j + 1];
}

// ---------------------------------------------------------------------------
// Generic tiny-batch (B=8) GEMM: out[b,j] = R[b,j] + act( bias[j] + LN?(X)[b,:] . W[j,:] )
//   - optional LN on X (and optional second LN stage), staged in dynamic LDS
//   - optional LN on residual R (stats only; values read from global)
//   - act: 0 = none, 1 = silu
//   - G lanes (power of 2) cooperate per output j, shuffle-reduced.
//   - blocks with blockIdx.x >= mmBlocks moonlight as A/mask row writers.
// ---------------------------------------------------------------------------
__global__ void head_mm(const float* __restrict__ X, int K,
                        const float* __restrict__ xlnw, const float* __restrict__ xlnb,
                        const float* __restrict__ xln2w, const float* __restrict__ xln2b,
                        const float* __restrict__ W, const float* __restrict__ bias,
                        const float* __restrict__ res,
                        const float* __restrict__ reslnw, const float* __restrict__ reslnb,
                        float* __restrict__ out, int J, int G, int act,
                        const float* __restrict__ psi,
                        float* __restrict__ Ao, float* __restrict__ Mo,
                        int mmBlocks, int arow0)
{
    const int bid = blockIdx.x;
    if (bid >= mmBlocks) {
        int r = arow0 + (bid - mmBlocks);
        if (r < NROWS) amask_row(psi, Ao, Mo, r);
        return;
    }

    extern __shared__ float sX[];           // 8*K floats when LN is active
    __shared__ float s_m[8], s_r[8], s_rm[8], s_rr[8];
    const int tid = threadIdx.x;
    const int row = tid >> 5, lane = tid & 31;   // 32 lanes per batch-row for stats
    const bool doLN = (xlnw != nullptr);
    const bool doRLN = (res != nullptr) && (reslnw != nullptr);

    if (doLN) {
        float s = 0.f, ss = 0.f;
        for (int k = lane; k < K; k += 32) {
            float v = X[row * K + k];
            s += v; ss += v * v;
        }
        for (int d = 16; d; d >>= 1) { s += __shfl_down(s, d); ss += __shfl_down(ss, d); }
        if (lane == 0) {
            float m = s / K;
            s_m[row] = m;
            s_r[row] = rsqrtf(ss / K - m * m + 1e-5f);
        }
    }
    if (doRLN) {
        float s = 0.f, ss = 0.f;
        for (int k = lane; k < J; k += 32) {
            float v = res[row * J + k];
            s += v; ss += v * v;
        }
        for (int d = 16; d; d >>= 1) { s += __shfl_down(s, d); ss += __shfl_down(ss, d); }
        if (lane == 0) {
            float m = s / J;
            s_rm[row] = m;
            s_rr[row] = rsqrtf(ss / J - m * m + 1e-5f);
        }
    }
    __syncthreads();

    if (doLN) {
        for (int idx = tid; idx < 8 * K; idx += 256) {
            int b = idx / K, k = idx - b * K;
            sX[idx] = (X[idx] - s_m[b]) * s_r[b] * xlnw[k] + xlnb[k];
        }
        __syncthreads();
        if (xln2w) {   // second LN stage (LN(LN(x)))
            float s = 0.f, ss = 0.f;
            for (int k = lane; k < K; k += 32) {
                float v = sX[row * K + k];
                s += v; ss += v * v;
            }
            for (int d = 16; d; d >>= 1) { s += __shfl_down(s, d); ss += __shfl_down(ss, d); }
            if (lane == 0) {
                float m = s / K;
                s_m[row] = m;
                s_r[row] = rsqrtf(ss / K - m * m + 1e-5f);
            }
            __syncthreads();
            for (int idx = tid; idx < 8 * K; idx += 256) {
                int b = idx / K, k = idx - b * K;
                sX[idx] = (sX[idx] - s_m[b]) * s_r[b] * xln2w[k] + xln2b[k];
            }
            __syncthreads();
        }
    }

    const float* __restrict__ Xp = doLN ? (const float*)sX : X;
    const int g = tid & (G - 1);
    const int jj = tid / G;
    const int j = bid * (256 / G) + jj;

    float acc[8] = {0.f, 0.f, 0.f, 0.f, 0.f, 0.f, 0.f, 0.f};
    if (j < J) {
        const float4* W4 = reinterpret_cast<const float4*>(W + (size_t)j * K);
        const int K4 = K >> 2;
        for (int i4 = g; i4 < K4; i4 += G) {
            float4 w4 = W4[i4];
            int k = i4 << 2;
            #pragma unroll
            for (int b = 0; b < 8; ++b) {
                float4 xv = *reinterpret_cast<const float4*>(Xp + b * K + k);
                acc[b] = fmaf(w4.x, xv.x, acc[b]);
                acc[b] = fmaf(w4.y, xv.y, acc[b]);
                acc[b] = fmaf(w4.z, xv.z, acc[b]);
                acc[b] = fmaf(w4.w, xv.w, acc[b]);
            }
        }
    }
    for (int d = G >> 1; d; d >>= 1) {
        #pragma unroll
        for (int b = 0; b < 8; ++b) acc[b] += __shfl_down(acc[b], d);
    }
    if (g == 0 && j < J) {
        float bs = bias ? bias[j] : 0.f;
        #pragma unroll
        for (int b = 0; b < 8; ++b) {
            float v = acc[b] + bs;
            if (act) v = v / (1.f + expf(-v));   // silu
            if (res) {
                float rv = res[(size_t)b * J + j];
                if (reslnw) rv = (rv - s_rm[b]) * s_rr[b] * reslnw[j] + reslnb[j];
                v += rv;
            }
            out[(size_t)b * J + j] = v;
        }
    }
}

// ---------------------------------------------------------------------------
extern "C" void kernel_launch(void* const* d_in, const int* in_sizes, int n_in,
                              void* d_out, int out_size, void* d_ws, size_t ws_size,
                              hipStream_t stream)
{
    const float* x      = (const float*)d_in[0];
    const float* proj_w = (const float*)d_in[1];
    const float* proj_b = (const float*)d_in[2];
    const float* pe     = (const float*)d_in[3];
    const float* hebb   = (const float*)d_in[4];
    const float* ai_w   = (const float*)d_in[5];
    const float* ai_b   = (const float*)d_in[6];
    const float* ao_w   = (const float*)d_in[7];
    const float* ao_b   = (const float*)d_in[8];
    const float* f1_w   = (const float*)d_in[9];
    const float* f1_b   = (const float*)d_in[10];
    const float* f2_w   = (const float*)d_in[11];
    const float* f2_b   = (const float*)d_in[12];
    const float* ln1w   = (const float*)d_in[13];
    const float* ln1b   = (const float*)d_in[14];
    const float* ln2w   = (const float*)d_in[15];
    const float* ln2b   = (const float*)d_in[16];
    const float* nAw    = (const float*)d_in[17];
    const float* nAb    = (const float*)d_in[18];
    const float* nBw    = (const float*)d_in[19];
    const float* nBb    = (const float*)d_in[20];
    const float* p1w    = (const float*)d_in[21];
    const float* p1b    = (const float*)d_in[22];
    const float* p2w    = (const float*)d_in[23];
    const float* p2b    = (const float*)d_in[24];

    float* out   = (float*)d_out;
    // output layout: preds(8) | A(B*S*S) | mask(B*S*S) | psi(B*S*2)
    float* preds = out;
    float* A     = out + 8;
    float* Mask  = out + 8 + (size_t)BB * SS * SS;
    float* Psi   = out + 8 + (size_t)2 * BB * SS * SS;

    float* ws = (float*)d_ws;
    float* Mc = ws;            // 514 (pad to 640)
    float* T  = ws + 640;      // 8x512 pre-LN state (starts as h0)
    float* V  = ws + 4736;     // 8x512
    float* T1 = ws + 8832;     // 8x512
    float* F  = ws + 12928;    // 8x2048
    float* P  = ws + 29312;    // 8x256

    compute_M<<<1, 1024, 0, stream>>>(proj_w, proj_b, pe, Mc);
    psi_kernel<<<NROWS / 16, 256, 0, stream>>>(x, Mc, Psi);

    // 15 carrier launches moonlight the 16384 A/mask rows (~1092 each).
    int ci = 0, arow = 0;
    auto nextq = [&]() { int q = 1092 + (ci < 4 ? 1 : 0); ++ci; return q; };

    {
        int q = nextq();
        h0_kernel<<<BB + q, 256, 0, stream>>>(Psi, hebb, T, A, Mask, arow);
        arow += q;
    }

    for (int l = 0; l < LL; ++l) {
        const float* pxw = l ? ln2w + (l - 1) * HH : nullptr;
        const float* pxb = l ? ln2b + (l - 1) * HH : nullptr;
        int q;
        // v = LN?(h) @ Wv^T + bv            (J=512, K=512, G=32 -> 64 mm blocks)
        q = nextq();
        head_mm<<<64 + q, 256, (pxw ? 8 * HH * 4 : 0), stream>>>(
            T, HH, pxw, pxb, nullptr, nullptr,
            ai_w + ((size_t)l * 3 * HH + 2 * HH) * HH, ai_b + l * 3 * HH + 2 * HH,
            nullptr, nullptr, nullptr, V, HH, 32, 0,
            Psi, A, Mask, 64, arow);
        arow += q;
        // t1 = LN?(T) + (v @ Wo^T + bo)     (J=512, K=512)
        q = nextq();
        head_mm<<<64 + q, 256, 0, stream>>>(
            V, HH, nullptr, nullptr, nullptr, nullptr,
            ao_w + (size_t)l * HH * HH, ao_b + l * HH,
            T, pxw, pxb, T1, HH, 32, 0,
            Psi, A, Mask, 64, arow);
        arow += q;
        // f = silu(LN(t1,ln1) @ W1^T + b1)  (J=2048, K=512, G=16 -> 128 mm blocks)
        q = nextq();
        head_mm<<<128 + q, 256, 8 * HH * 4, stream>>>(
            T1, HH, ln1w + l * HH, ln1b + l * HH, nullptr, nullptr,
            f1_w + (size_t)l * 4 * HH * HH, f1_b + l * 4 * HH,
            nullptr, nullptr, nullptr, F, 4 * HH, 16, 1,
            Psi, A, Mask, 128, arow);
        arow += q;
        // t2 = LN(t1,ln1) + (f @ W2^T + b2) (J=512, K=2048, G=64 -> 128 mm blocks)
        q = nextq();
        head_mm<<<128 + q, 256, 0, stream>>>(
            F, 4 * HH, nullptr, nullptr, nullptr, nullptr,
            f2_w + (size_t)l * HH * 4 * HH, f2_b + l * HH,
            T1, ln1w + l * HH, ln1b + l * HH, T, HH, 64, 0,
            Psi, A, Mask, 128, arow);
        arow += q;
    }
    // p = silu( LN(LN(t2,ln2[2]),normA) @ p1^T + p1_b )   (J=256, K=512)
    {
        int q = nextq();
        head_mm<<<32 + q, 256, 8 * HH * 4, stream>>>(
            T, HH, ln2w + 2 * HH, ln2b + 2 * HH, nAw, nAb,
            p1w, p1b, nullptr, nullptr, nullptr, P, HH / 2, 32, 1,
            Psi, A, Mask, 32, arow);
        arow += q;
    }
    // preds = LN(p,normB) @ p2^T + p2_b                   (J=1, K=256)
    {
        int q = nextq();
        head_mm<<<1 + q, 256, 8 * (HH / 2) * 4, stream>>>(
            P, HH / 2, nBw, nBb, nullptr, nullptr,
            p2w, p2b, nullptr, nullptr, nullptr, preds, 1, 32, 0,
            Psi, A, Mask, 1, arow);
        arow += q;
    }
}